// Round 5
// baseline (8904.559 us; speedup 1.0000x reference)
//
#include <hip/hip_runtime.h>

#define MSCOPE __HIP_MEMORY_SCOPE_AGENT

// ---------------- model dims ----------------
// V=50000 E=128 H=160 D=196 A=224 BN=56, B=32, Tin=256, Ttgt=100
// encoder gates 4H=640, decoder gates 4D=784, 2H=320, D+2H=516, V-END=49998
// X layouts: Xf/Xb/Xd = [t*32+b][gates]   (row-major per (t,b))
// WhT layouts (k-major): T[((k>>2)*C + c)*4 + (k&3)] = Wh[c][k],  C=#gate-rows

// ---------------- ws float layout ----------------
constexpr size_t oXf   = 0;                                // 8192 x 640
constexpr size_t oXb   = oXf   + (size_t)8192*640;
constexpr size_t oXd   = oXb   + (size_t)8192*640;         // 3200 x 784
constexpr size_t oHenc = oXd   + (size_t)3200*784;         // [dir*256+t][b*160+j]
constexpr size_t oEncA = oHenc + (size_t)2*256*5120;       // 8192 x 224
constexpr size_t oEs   = oEncA + (size_t)8192*224;         // 3200
constexpr size_t oCT   = oEs   + 3200;                     // 2 x 5120
constexpr size_t oH0   = oCT   + 10240;                    // 32 x 196
constexpr size_t oC0   = oH0   + 6272;                     // 32 x 196
constexpr size_t oHWdsAll = oC0 + 6272;                    // 100 x 32
constexpr size_t oCtxWAll = oHWdsAll + 3200;
constexpr size_t oCopyAll = oCtxWAll + 3200;
constexpr size_t oZidxAll = oCopyAll + 3200;
constexpr size_t oClAll   = oZidxAll + 3200;               // 32
constexpr size_t oNllWg   = oClAll + 32;                   // 224
constexpr size_t oWfT     = oNllWg + 224;                  // 160x640 k-major
constexpr size_t oWbT     = oWfT + 102400;
constexpr size_t oWdT     = oWbT + 102400;                 // 196x784 k-major
constexpr size_t oFEnd    = oWdT + 153664;
// dec-phase overlays on the (dead) Xf region:
constexpr size_t oUAll    = 0;                             // 100 x 32 x 56
constexpr size_t oPartAll = (size_t)100*1792;              // 100 x 32 x 224
// ints after floats: in_mapped[8192], cur_ids[3200], flags[3648]
constexpr int fP2  = 0;       // 100*32
constexpr int fP3  = 3200;    // 224
constexpr int fFin = 3424;    // 224
constexpr int fEnd = 3648;

// ---------------- helpers ----------------
__device__ __forceinline__ float fast_tanh(float x){
  float e = __expf(-2.f*fabsf(x));
  float r = (1.f - e) * __builtin_amdgcn_rcpf(1.f + e);
  return copysignf(r, x);
}
__device__ __forceinline__ float sigm(float x){
  return __builtin_amdgcn_rcpf(1.f + __expf(-x));
}
__device__ __forceinline__ float aload(const float* p){
  return __hip_atomic_load(const_cast<float*>(p), __ATOMIC_RELAXED, MSCOPE);
}
__device__ __forceinline__ float2 aload2(const float* p){
  unsigned long long u = __hip_atomic_load(
      reinterpret_cast<unsigned long long*>(const_cast<float*>(p)),
      __ATOMIC_RELAXED, MSCOPE);
  float2 r; __builtin_memcpy(&r, &u, 8); return r;
}
__device__ __forceinline__ void astore(float* p, float v){
  __hip_atomic_store(p, v, __ATOMIC_RELAXED, MSCOPE);
}
__device__ __forceinline__ void wait_slots(unsigned* slots, int n, int tid){
  if (tid < 64){
    for(;;){
      bool miss = false;
      for (int i = tid; i < n; i += 64)
        if (__hip_atomic_load(&slots[i], __ATOMIC_RELAXED, MSCOPE) == 0u) miss = true;
      if (__ballot(miss) == 0ULL) break;
      __builtin_amdgcn_s_sleep(8);
    }
  }
  __syncthreads();
}
// producers: __syncthreads() (drains vmcnt, stores ack'd at LLC) BEFORE set_slot
__device__ __forceinline__ void set_slot(unsigned* slot){
  __hip_atomic_store(slot, 1u, __ATOMIC_RELAXED, MSCOPE);
}
__device__ __forceinline__ float block_sum(float v, float* red){
  #pragma unroll
  for (int o=32;o;o>>=1) v += __shfl_down(v,o);
  if ((threadIdx.x&63)==0) red[threadIdx.x>>6] = v;
  __syncthreads();
  v = red[0]+red[1]+red[2]+red[3];
  __syncthreads();
  return v;
}

// ---------------- prep: id mapping + flag zeroing ----------------
__global__ void prep_kernel(const int* __restrict__ in_ids, const int* __restrict__ tgt,
                            int* __restrict__ in_mapped, int* __restrict__ cur_ids,
                            unsigned* __restrict__ flags){
  int i = blockIdx.x*256 + threadIdx.x;
  if (i < 8192){
    int t = i >> 5, b = i & 31;
    int id = in_ids[b*256 + t];
    in_mapped[i] = (id >= 50000) ? 3 : id;
  }
  if (i < 3200){
    int k = i >> 5, b = i & 31;
    int id = (k == 0) ? 1 : tgt[b*100 + (k-1)];
    cur_ids[i] = (id >= 50000) ? 3 : id;
  }
  if (i < fEnd) flags[i] = 0u;
}

// ---------------- k-major transpose: T[((k>>2)*C+c)*4+(k&3)] = W[c*K+k] --------
__global__ void transpose4(const float* __restrict__ W, float* __restrict__ T,
                           int C, int K){
  int total = C*K;
  for (int i = blockIdx.x*256 + threadIdx.x; i < total; i += gridDim.x*256){
    int c = i / K, kk = i - c*K;
    T[((size_t)(kk>>2)*C + c)*4 + (kk&3)] = W[i];
  }
}

// ------- rowgemm (emb gather): out[r][g] = sum_k emb[gid[r]][k]*W[g][k]+b1+b2 ---
struct RGArgs{ const int* gid; const float* emb; const float* W;
               const float* bias1; const float* bias2; float* out; int N; };
__global__ void __launch_bounds__(256) rowgemm(RGArgs a){
  __shared__ float rl[8*128];
  const int tid = threadIdx.x;
  const int N = a.N;
  const size_t r0 = (size_t)blockIdx.x*8;
  for (int i = tid; i < 8*128; i += 256){
    int r = i >> 7, k = i & 127;
    rl[i] = a.emb[(size_t)a.gid[r0+r]*128 + k];
  }
  __syncthreads();
  for (int g = tid; g < N; g += 256){
    const float* wr = a.W + (size_t)g*128;
    float acc[8];
    #pragma unroll
    for (int r=0;r<8;r++) acc[r]=0.f;
    for (int k=0;k<128;k+=4){
      float4 wv = *(const float4*)(wr+k);
      #pragma unroll
      for (int r=0;r<8;r++){
        float4 xv = *(const float4*)(rl + r*128 + k);
        acc[r] += wv.x*xv.x + wv.y*xv.y + wv.z*xv.z + wv.w*xv.w;
      }
    }
    float bias = a.bias1[g] + a.bias2[g];
    #pragma unroll
    for (int r=0;r<8;r++) a.out[(r0+r)*(size_t)N + g] = acc[r] + bias;
  }
}

// ---------------- es[r] = emb[gid[r]] . Wes ----------------
__global__ void es_kernel(const int* __restrict__ gid, const float* __restrict__ emb,
                          const float* __restrict__ Wes, float* __restrict__ es){
  int r = blockIdx.x, l = threadIdx.x;
  const float* e = emb + (size_t)gid[r]*128;
  float acc = e[l]*Wes[l] + e[l+64]*Wes[l+64];
  #pragma unroll
  for (int o=32;o;o>>=1) acc += __shfl_down(acc,o);
  if (l==0) es[r] = acc;
}

// -------- encoder: per-(dir, 2 batches) WG, zero inter-WG sync, 32 WGs --------
struct EncArgs{ const float* Xf; const float* Xb; const float* WfT; const float* WbT;
                float* henc; float* cT; };
__global__ void __launch_bounds__(320) enc_scan(EncArgs a){
  __shared__ float hl[320];
  const int wg = blockIdx.x;
  const int dir = wg >> 4, bp = wg & 15;
  const int tid = threadIdx.x;
  const int bl = tid / 160, j = tid - bl*160;
  const int b = bp*2 + bl;
  const float* X = dir ? a.Xb : a.Xf;
  const float* T = dir ? a.WbT : a.WfT;
  float* H = a.henc + (size_t)dir*256*5120;
  float c = 0.f;
  hl[tid] = 0.f;
  __syncthreads();
  for (int t = 0; t < 256; ++t){
    const int trow = dir ? 255 - t : t;
    const float* xr = X + ((size_t)trow*32 + b)*640 + j;
    float g0 = xr[0], g1 = xr[160], g2 = xr[320], g3 = xr[480];
    const float* hb = hl + bl*160;
    #pragma unroll 4
    for (int k4 = 0; k4 < 40; ++k4){
      float4 h4 = *(const float4*)(hb + k4*4);
      const float4* Tr = (const float4*)(T + (size_t)k4*2560);
      float4 w0 = Tr[j], w1 = Tr[160+j], w2 = Tr[320+j], w3 = Tr[480+j];
      g0 += w0.x*h4.x + w0.y*h4.y + w0.z*h4.z + w0.w*h4.w;
      g1 += w1.x*h4.x + w1.y*h4.y + w1.z*h4.z + w1.w*h4.w;
      g2 += w2.x*h4.x + w2.y*h4.y + w2.z*h4.z + w2.w*h4.w;
      g3 += w3.x*h4.x + w3.y*h4.y + w3.z*h4.z + w3.w*h4.w;
    }
    float ig = sigm(g0), fg = sigm(g1), gc = fast_tanh(g2), og = sigm(g3);
    c = fg*c + ig*gc;
    float h = og * fast_tanh(c);
    __syncthreads();
    hl[tid] = h;
    H[(size_t)trow*5120 + b*160 + j] = h;
    __syncthreads();
  }
  a.cT[dir*5120 + b*160 + j] = c;
}

// ---------------- mid: h0/c0 projections ----------------
__global__ void mid_kernel(const float* __restrict__ henc, const float* __restrict__ cT,
                           const float* __restrict__ Weh, const float* __restrict__ beh,
                           const float* __restrict__ Wec, const float* __restrict__ bec,
                           float* __restrict__ h0, float* __restrict__ c0){
  __shared__ float hc[320], cc[320];
  int b = blockIdx.x, tid = threadIdx.x;
  if (tid < 160){
    hc[tid]     = henc[(size_t)255*5120 + b*160 + tid];
    hc[160+tid] = henc[(size_t)256*5120 + b*160 + tid];
    cc[tid]     = cT[b*160 + tid];
    cc[160+tid] = cT[5120 + b*160 + tid];
  }
  __syncthreads();
  for (int g = tid; g < 196; g += 256){
    const float* w1 = Weh + (size_t)g*320;
    const float* w2 = Wec + (size_t)g*320;
    float a1 = beh[g], a2 = bec[g];
    for (int k = 0; k < 320; ++k){ a1 += hc[k]*w1[k]; a2 += cc[k]*w2[k]; }
    h0[b*196 + g] = a1;
    c0[b*196 + g] = a2;
  }
}

// ---------------- encA = [hf;hb] @ Wea.T + bea ----------------
__global__ void __launch_bounds__(256) encA_gemm(const float* __restrict__ henc,
                 const float* __restrict__ Wea, const float* __restrict__ bea,
                 float* __restrict__ encA){
  __shared__ float rl[8*320];
  const int tid = threadIdx.x;
  const size_t r0 = (size_t)blockIdx.x*8;
  for (int i = tid; i < 8*320; i += 256){
    int r = i/320, k = i - r*320;
    size_t row = r0 + r; int b = (int)(row >> 8), t = (int)(row & 255);
    rl[i] = (k < 160) ? henc[(size_t)t*5120 + b*160 + k]
                      : henc[(size_t)(256+t)*5120 + b*160 + (k-160)];
  }
  __syncthreads();
  for (int g = tid; g < 224; g += 256){
    const float* wr = Wea + (size_t)g*320;
    float acc[8];
    #pragma unroll
    for (int r=0;r<8;r++) acc[r]=0.f;
    for (int k=0;k<320;k+=4){
      float4 wv = *(const float4*)(wr+k);
      #pragma unroll
      for (int r=0;r<8;r++){
        float4 xv = *(const float4*)(rl + r*320 + k);
        acc[r] += wv.x*xv.x + wv.y*xv.y + wv.z*xv.z + wv.w*xv.w;
      }
    }
    float bias = bea[g];
    #pragma unroll
    for (int r=0;r<8;r++) encA[(r0+r)*224 + g] = acc[r] + bias;
  }
}

// ---------------- decoder (cooperative, grid=256) ----------------
struct DecArgs{
  const float* Xd; const float* henc; const float* encA;
  const float* h0; const float* c0; const float* WdT;
  const float* Wda; const float* Wca; const float* vat;
  const float* W1; const float* b1; const float* W2; const float* b2;
  const float* Wcs; const float* bcs; const float* Wds; const float* es;
  const int* in_ids; const int* tgt;
  float* uAll; float* hWdsAll; float* ctxWAll; float* copyAll;
  float* zidxAll; float* partAll; float* clAll; float* nllWg; float* out;
  unsigned* flg;
};

__global__ void __launch_bounds__(256) dec_scan(DecArgs A){
  extern __shared__ float sm[];
  const int wg = blockIdx.x, tid = threadIdx.x;
  unsigned* fP2P  = A.flg + fP2;
  unsigned* fP3P  = A.flg + fP3;
  unsigned* fFinP = A.flg + fFin;

  if (wg < 32){
    // ======== per-batch chain: LSTM -> attention -> ctx -> u (no waits) ========
    const int b = wg;
    float* hl2   = sm;           // 200
    float* hwda  = sm + 200;     // 224
    float* attnL = sm + 424;     // 256
    float* pctx  = sm + 680;     // 960
    float* ctxL  = sm + 1640;    // 320
    float* red   = sm + 1960;    // 4
    float* wcaL  = sm + 1964;    // 224
    float* vL    = sm + 2188;    // 224
    float* WcsL  = sm + 2412;    // 320
    float* b1L   = sm + 2732;    // 56
    float* WdsL  = sm + 2788;    // 196
    if (tid < 224){ wcaL[tid] = A.Wca[tid]; vL[tid] = A.vat[tid]; }
    for (int i = tid; i < 320; i += 256) WcsL[i] = A.Wcs[i];
    if (tid < 56)  b1L[tid]  = A.b1[tid];
    if (tid < 196) WdsL[tid] = A.Wds[tid];
    if (tid < 196) hl2[tid]  = A.h0[b*196 + tid];
    const int j = tid;
    float c = (j < 196) ? A.c0[b*196 + j] : 0.f;
    const int inid = A.in_ids[b*256 + tid];
    const float4* erow = (const float4*)(A.encA + (size_t)(b*256 + tid)*224);
    float cov = 0.f, clr = 0.f;
    __syncthreads();
    for (int s = 0; s < 100; ++s){
      // ---- LSTM (WdT k-major from L2, h broadcast from LDS) ----
      float g0=0.f,g1=0.f,g2=0.f,g3=0.f;
      if (j < 196){
        const float* xr = A.Xd + ((size_t)s*32 + b)*784 + j;
        g0 = xr[0]; g1 = xr[196]; g2 = xr[392]; g3 = xr[588];
        #pragma unroll 7
        for (int k4 = 0; k4 < 49; ++k4){
          float4 h4 = *(const float4*)(hl2 + k4*4);
          const float4* Tr = (const float4*)(A.WdT + (size_t)k4*3136);
          float4 w0 = Tr[j], w1 = Tr[196+j], w2 = Tr[392+j], w3 = Tr[588+j];
          g0 += w0.x*h4.x + w0.y*h4.y + w0.z*h4.z + w0.w*h4.w;
          g1 += w1.x*h4.x + w1.y*h4.y + w1.z*h4.z + w1.w*h4.w;
          g2 += w2.x*h4.x + w2.y*h4.y + w2.z*h4.z + w2.w*h4.w;
          g3 += w3.x*h4.x + w3.y*h4.y + w3.z*h4.z + w3.w*h4.w;
        }
      }
      __syncthreads();
      if (j < 196){
        float ig = sigm(g0), fg = sigm(g1), gc = fast_tanh(g2), og = sigm(g3);
        c = fg*c + ig*gc;
        hl2[j] = og * fast_tanh(c);
      }
      __syncthreads();
      // ---- hwda + hWds ----
      if (tid < 224){
        const float* wr = A.Wda + (size_t)tid*196;
        float acc = 0.f;
        #pragma unroll 4
        for (int q = 0; q < 196; ++q) acc += hl2[q]*wr[q];
        hwda[tid] = acc;
      } else {
        int l = tid - 224; float acc = 0.f;
        for (int q = l; q < 196; q += 32) acc += hl2[q]*WdsL[q];
        #pragma unroll
        for (int o=16;o;o>>=1) acc += __shfl_down(acc,o,32);
        if (l==0) astore(&A.hWdsAll[s*32 + b], acc);
      }
      __syncthreads();
      // ---- attention scores + softmax ----
      float exv = 0.f;
      if (inid != 0){
        float acc = 0.f;
        #pragma unroll 8
        for (int q = 0; q < 56; ++q){
          float4 ev = erow[q]; int a0 = 4*q;
          acc += fast_tanh(ev.x + hwda[a0]   + cov*wcaL[a0]  )*vL[a0];
          acc += fast_tanh(ev.y + hwda[a0+1] + cov*wcaL[a0+1])*vL[a0+1];
          acc += fast_tanh(ev.z + hwda[a0+2] + cov*wcaL[a0+2])*vL[a0+2];
          acc += fast_tanh(ev.w + hwda[a0+3] + cov*wcaL[a0+3])*vL[a0+3];
        }
        exv = __expf(acc);
      }
      float S = block_sum(exv, red);
      float attn = exv * __builtin_amdgcn_rcpf(S);
      attnL[tid] = attn;
      const int ntb = A.tgt[b*100 + s];
      float cpS = block_sum((inid == ntb) ? attn : 0.f, red);
      float mnS = block_sum(fminf(attn, cov), red);
      if (tid == 0){
        astore(&A.copyAll[s*32 + b], cpS);
        clr += mnS;
        if (s == 99) astore(&A.clAll[b], clr);
      }
      cov += attn;
      // ---- ctx ----
      if (tid < 240){
        int seg = tid/80, h4i = tid - seg*80;
        int t0 = seg*86, t1 = (t0+86 < 256) ? t0+86 : 256;
        const float* base = (h4i < 40)
          ? (A.henc + (size_t)b*160 + (size_t)h4i*4)
          : (A.henc + (size_t)256*5120 + (size_t)b*160 + (size_t)(h4i-40)*4);
        float4 accv = {0.f,0.f,0.f,0.f};
        #pragma unroll 4
        for (int t2 = t0; t2 < t1; ++t2){
          float av = attnL[t2];
          float4 ev = *(const float4*)(base + (size_t)t2*5120);
          accv.x += av*ev.x; accv.y += av*ev.y; accv.z += av*ev.z; accv.w += av*ev.w;
        }
        *(float4*)(pctx + (seg*80+h4i)*4) = accv;
      }
      __syncthreads();
      if (tid < 80){
        float4 p0 = *(float4*)(pctx + tid*4);
        float4 p1 = *(float4*)(pctx + (80+tid)*4);
        float4 p2v = *(float4*)(pctx + (160+tid)*4);
        float4 cvv;
        cvv.x = p0.x+p1.x+p2v.x; cvv.y = p0.y+p1.y+p2v.y;
        cvv.z = p0.z+p1.z+p2v.z; cvv.w = p0.w+p1.w+p2v.w;
        *(float4*)(ctxL + tid*4) = cvv;
      }
      __syncthreads();
      // ---- u + ctxWcs ----
      if (tid < 224){
        int g = tid >> 2, ks = tid & 3;
        const float* wr = A.W1 + (size_t)g*516;
        float acc = 0.f;
        #pragma unroll 4
        for (int q = ks; q < 516; q += 4){
          float hv = (q < 196) ? hl2[q] : ctxL[q-196];
          acc += hv*wr[q];
        }
        acc += __shfl_down(acc,2,4); acc += __shfl_down(acc,1,4);
        if (ks == 0) astore(&A.uAll[(size_t)s*1792 + b*56 + g], fast_tanh(acc + b1L[g]));
      } else {
        int l = tid - 224; float acc = 0.f;
        for (int q = l; q < 320; q += 32) acc += ctxL[q]*WcsL[q];
        #pragma unroll
        for (int o=16;o;o>>=1) acc += __shfl_down(acc,o,32);
        if (l==0) astore(&A.ctxWAll[s*32 + b], acc);
      }
      __syncthreads();                 // drain vmcnt: u/scalars at LLC
      if (tid == 0) set_slot(fP2P + s*32 + b);
    }
    return;
  }

  // ======== P3: vocab sum-exp; W2 row pinned in registers (224 WGs) ========
  {
    const int wgv = wg - 32;
    const int vs = (wgv*49998)/224, ve = ((wgv+1)*49998)/224;
    const int v = vs + tid;
    const bool valid = v < ve;
    const int vc = valid ? v : 0;
    float4 w2r[14];
    {
      const float4* wr = (const float4*)(A.W2 + (size_t)vc*56);
      #pragma unroll
      for (int q=0;q<14;++q) w2r[q] = wr[q];
    }
    const float b2v = A.b2[vc];
    float* ulL  = sm;                  // 1792
    float* redW = sm + 1792;           // 128
    int*   idxL = (int*)(sm + 1920);   // 32
    float* red  = sm + 2048;           // 4
    const int lane = tid & 63, wv2 = tid >> 6;
    for (int s = 0; s < 100; ++s){
      int nt3 = (tid < 32) ? A.tgt[tid*100 + s] : 0;
      wait_slots(fP2P + s*32, 32, tid);
      for (int i2 = tid; i2 < 896; i2 += 256){
        float2 u2 = aload2(&A.uAll[(size_t)s*1792 + i2*2]);
        *(float2*)(ulL + i2*2) = u2;
      }
      if (tid < 32){
        int ix = nt3 - 2; ix = ix<0?0:(ix>49997?49997:ix);
        idxL[tid] = ix;
      }
      __syncthreads();
      #pragma unroll 4
      for (int bb=0; bb<32; ++bb){
        const float4* uv = (const float4*)(ulL + bb*56);
        float z = b2v;
        #pragma unroll
        for (int q=0;q<14;++q){
          float4 u4 = uv[q];
          z += w2r[q].x*u4.x + w2r[q].y*u4.y + w2r[q].z*u4.z + w2r[q].w*u4.w;
        }
        if (valid && v == idxL[bb]) astore(&A.zidxAll[s*32+bb], z);
        float sv2 = valid ? __expf(z) : 0.f;
        #pragma unroll
        for (int o=32;o;o>>=1) sv2 += __shfl_down(sv2,o);
        if (lane == 0) redW[wv2*32+bb] = sv2;
      }
      __syncthreads();
      if (tid < 32){
        float tot = redW[tid]+redW[32+tid]+redW[64+tid]+redW[96+tid];
        astore(&A.partAll[(size_t)(s*32+tid)*224 + wgv], tot);
      }
      __syncthreads();
    }
    __syncthreads();
    if (tid == 0) set_slot(fP3P + wgv);
    // ---- finalize stage 1 ----
    wait_slots(fP3P, 224, tid);
    float nll1 = 0.f;
    for (int p = wgv; p < 3200; p += 224){
      float pv = (tid < 224) ? aload(&A.partAll[(size_t)p*224 + tid]) : 0.f;
      float se = block_sum(pv, red);
      if (tid == 0){
        int s = p >> 5, b = p & 31;
        int nt2 = A.tgt[b*100 + s];
        float xg = aload(&A.ctxWAll[p]) + A.bcs[0] + aload(&A.hWdsAll[p]) + A.es[p];
        float pg = 1.f/(1.f + __expf(-xg));
        float genp = (nt2 >= 2 && nt2 < 50000) ? (__expf(aload(&A.zidxAll[p])) / se) : 0.f;
        float pr = pg*genp + (1.f-pg)*aload(&A.copyAll[p]);
        nll1 += -logf(pr + 1e-9f);
      }
    }
    if (tid == 0) astore(&A.nllWg[wgv], nll1);
    __syncthreads();
    if (tid == 0) set_slot(fFinP + wgv);
    // ---- finalize stage 2 (one WG) ----
    if (wg == 32){
      wait_slots(fFinP, 224, tid);
      float nv = (tid < 224) ? aload(&A.nllWg[tid]) : 0.f;
      float nll = block_sum(nv, red);
      float cv = (tid < 32) ? aload(&A.clAll[tid]) : 0.f;
      float cl = block_sum(cv, red);
      if (tid == 0){ A.out[0]=nll; A.out[1]=cl; A.out[2]=nll + 0.75f*cl; }
    }
  }
}

// ---------------- host launch ----------------
extern "C" void kernel_launch(void* const* d_in, const int* in_sizes, int n_in,
                              void* d_out, int out_size, void* d_ws, size_t ws_size,
                              hipStream_t stream){
  const int*   in_ids = (const int*)  d_in[0];
  const int*   tgt    = (const int*)  d_in[1];
  const float* emb    = (const float*)d_in[3];
  const float* Wi_f   = (const float*)d_in[4];
  const float* Wh_f   = (const float*)d_in[5];
  const float* bi_f   = (const float*)d_in[6];
  const float* bh_f   = (const float*)d_in[7];
  const float* Wi_b   = (const float*)d_in[8];
  const float* Wh_b   = (const float*)d_in[9];
  const float* bi_b   = (const float*)d_in[10];
  const float* bh_b   = (const float*)d_in[11];
  const float* Weh    = (const float*)d_in[12];
  const float* beh    = (const float*)d_in[13];
  const float* Wec    = (const float*)d_in[14];
  const float* bec    = (const float*)d_in[15];
  const float* Wi_d   = (const float*)d_in[16];
  const float* Wh_d   = (const float*)d_in[17];
  const float* bi_d   = (const float*)d_in[18];
  const float* bh_d   = (const float*)d_in[19];
  const float* Wea    = (const float*)d_in[20];
  const float* bea    = (const float*)d_in[21];
  const float* Wda    = (const float*)d_in[22];
  const float* Wca    = (const float*)d_in[23];
  const float* vat    = (const float*)d_in[24];
  const float* W1     = (const float*)d_in[25];
  const float* b1     = (const float*)d_in[26];
  const float* W2     = (const float*)d_in[27];
  const float* b2     = (const float*)d_in[28];
  const float* Wcs    = (const float*)d_in[29];
  const float* bcs    = (const float*)d_in[30];
  const float* Wds    = (const float*)d_in[31];
  const float* Wes    = (const float*)d_in[32];

  float* ws = (float*)d_ws;
  int* iBase = (int*)(ws + oFEnd);
  int* in_mapped = iBase;
  int* cur_ids   = iBase + 8192;
  unsigned* flags = (unsigned*)(iBase + 11392);

  prep_kernel<<<32, 256, 0, stream>>>(in_ids, tgt, in_mapped, cur_ids, flags);

  transpose4<<<256, 256, 0, stream>>>(Wh_f, ws + oWfT, 640, 160);
  transpose4<<<256, 256, 0, stream>>>(Wh_b, ws + oWbT, 640, 160);
  transpose4<<<256, 256, 0, stream>>>(Wh_d, ws + oWdT, 784, 196);

  { RGArgs a{in_mapped, emb, Wi_f, bi_f, bh_f, ws + oXf, 640};
    rowgemm<<<1024, 256, 0, stream>>>(a); }
  { RGArgs a{in_mapped, emb, Wi_b, bi_b, bh_b, ws + oXb, 640};
    rowgemm<<<1024, 256, 0, stream>>>(a); }
  { RGArgs a{cur_ids, emb, Wi_d, bi_d, bh_d, ws + oXd, 784};
    rowgemm<<<400, 256, 0, stream>>>(a); }

  es_kernel<<<3200, 64, 0, stream>>>(cur_ids, emb, Wes, ws + oEs);

  { EncArgs ea{ws + oXf, ws + oXb, ws + oWfT, ws + oWbT, ws + oHenc, ws + oCT};
    enc_scan<<<32, 320, 0, stream>>>(ea); }

  mid_kernel<<<32, 256, 0, stream>>>(ws + oHenc, ws + oCT, Weh, beh, Wec, bec,
                                     ws + oH0, ws + oC0);

  encA_gemm<<<1024, 256, 0, stream>>>(ws + oHenc, Wea, bea, ws + oEncA);

  { DecArgs da{ws + oXd, ws + oHenc, ws + oEncA,
               ws + oH0, ws + oC0, ws + oWdT,
               Wda, Wca, vat,
               W1, b1, W2, b2, Wcs, bcs, Wds, ws + oEs,
               in_ids, tgt,
               ws + oUAll, ws + oHWdsAll, ws + oCtxWAll, ws + oCopyAll,
               ws + oZidxAll, ws + oPartAll, ws + oClAll, ws + oNllWg, (float*)d_out,
               flags};
    void* ka[] = {&da};
    hipLaunchCooperativeKernel((void*)dec_scan, dim3(256), dim3(256), ka,
                               (unsigned)(3072*4), stream); }
}

// Round 7
// 5057.360 us; speedup vs baseline: 1.7607x; 1.7607x over previous
//
#include <hip/hip_runtime.h>

#define MSCOPE __HIP_MEMORY_SCOPE_AGENT

// ---------------- model dims ----------------
// V=50000 E=128 H=160 D=196 A=224 BN=56, B=32, Tin=256, Ttgt=100
// X layouts: Xf/Xb/Xd = [t*32+b][gates]
// hencB layout: [dir*32+b][t][160]

// ---------------- ws float layout ----------------
constexpr size_t oXf   = 0;                                // 8192 x 640
constexpr size_t oXb   = oXf   + (size_t)8192*640;
constexpr size_t oXd   = oXb   + (size_t)8192*640;         // 3200 x 784
constexpr size_t oHencB= oXd   + (size_t)3200*784;         // 64 x 256 x 160
constexpr size_t oEncA = oHencB+ (size_t)64*256*160;       // 8192 x 224
constexpr size_t oEs   = oEncA + (size_t)8192*224;         // 3200
constexpr size_t oCT   = oEs   + 3200;                     // 2 x 5120
constexpr size_t oH0   = oCT   + 10240;                    // 32 x 196
constexpr size_t oC0   = oH0   + 6272;                     // 32 x 196
constexpr size_t oHWdsAll = oC0 + 6272;                    // 100 x 32
constexpr size_t oCtxWAll = oHWdsAll + 3200;
constexpr size_t oCopyAll = oCtxWAll + 3200;
constexpr size_t oZidxAll = oCopyAll + 3200;
constexpr size_t oClAll   = oZidxAll + 3200;               // 32
constexpr size_t oNllWg   = oClAll + 32;                   // 224
constexpr size_t oW1cT    = oNllWg + 224;                  // 320 x 56
constexpr size_t oFEnd    = oW1cT + 17920;
// dec-phase overlays on the (dead) Xf region:
constexpr size_t oHdAll   = 0;                             // 100 x 6272
constexpr size_t oUAll    = oHdAll + (size_t)100*6272;     // 100 x 1792
constexpr size_t oUPreAll = oUAll  + (size_t)100*1792;     // 100 x 1792
constexpr size_t oHwdaAll = oUPreAll + (size_t)100*1792;   // 100 x 32 x 224
constexpr size_t oPartAll = oHwdaAll + (size_t)100*7168;   // 100 x 32 x 224
// ints after floats: in_mapped[8192], cur_ids[3200], flags[17800]
// flag offsets (ints, relative to flags base); each mask word on its own 64B line
#define ENCW(d,t)  (((d)*256 + (t))*16)
#define FLSTM(s)   (8192 + (s)*16)
#define FAUX(s)    (9792 + (s)*16)
#define FP2W(s,m)  (11392 + (s)*64 + (m)*16)
#define CP3        17792
#define CFIN       17793
constexpr int fEnd = 17800;
constexpr unsigned ENC_FULL  = 0xFFFFFu;     // 20 bits
constexpr unsigned LSTM_FULL = 0x1FFFFFFu;   // 25 bits
constexpr unsigned P2_FULL   = 0xFFFFFFFFu;  // 32 bits

// ---------------- helpers ----------------
__device__ __forceinline__ float fast_tanh(float x){
  float e = __expf(-2.f*fabsf(x));
  float r = (1.f - e) * __builtin_amdgcn_rcpf(1.f + e);
  return copysignf(r, x);
}
__device__ __forceinline__ float sigm(float x){
  return __builtin_amdgcn_rcpf(1.f + __expf(-x));
}
// relaxed agent-scope: LLC-coherent, no L2 wb/inv
__device__ __forceinline__ float aload(const float* p){
  return __hip_atomic_load(const_cast<float*>(p), __ATOMIC_RELAXED, MSCOPE);
}
__device__ __forceinline__ float2 aload2(const float* p){
  unsigned long long u = __hip_atomic_load(
      reinterpret_cast<unsigned long long*>(const_cast<float*>(p)),
      __ATOMIC_RELAXED, MSCOPE);
  float2 r; __builtin_memcpy(&r, &u, 8); return r;
}
__device__ __forceinline__ void astore(float* p, float v){
  __hip_atomic_store(p, v, __ATOMIC_RELAXED, MSCOPE);
}
// single-lane poll of one mask word; others park at barrier (no poll storm)
template<int SLP>
__device__ __forceinline__ void wait_mask(unsigned* word, unsigned target, int tid){
  if (tid == 0){
    while (__hip_atomic_load(word, __ATOMIC_RELAXED, MSCOPE) != target)
      __builtin_amdgcn_s_sleep(SLP);
  }
  __syncthreads();
}
// producers: __syncthreads() (drains vmcnt -> data ack'd at LLC) BEFORE or_bit
__device__ __forceinline__ void or_bit(unsigned* word, unsigned bit){
  (void)__hip_atomic_fetch_or(word, bit, __ATOMIC_RELAXED, MSCOPE);
}
__device__ __forceinline__ void add1(unsigned* word){
  (void)__hip_atomic_fetch_add(word, 1u, __ATOMIC_RELAXED, MSCOPE);
}
__device__ __forceinline__ float block_sum(float v, float* red){
  #pragma unroll
  for (int o=32;o;o>>=1) v += __shfl_down(v,o);
  if ((threadIdx.x&63)==0) red[threadIdx.x>>6] = v;
  __syncthreads();
  v = red[0]+red[1]+red[2]+red[3];
  __syncthreads();
  return v;
}

// ---------------- prep: id mapping + flag zeroing ----------------
__global__ void prep_kernel(const int* __restrict__ in_ids, const int* __restrict__ tgt,
                            int* __restrict__ in_mapped, int* __restrict__ cur_ids,
                            unsigned* __restrict__ flags){
  int i = blockIdx.x*256 + threadIdx.x;
  if (i < 8192){
    int t = i >> 5, b = i & 31;
    int id = in_ids[b*256 + t];
    in_mapped[i] = (id >= 50000) ? 3 : id;
  }
  if (i < 3200){
    int k = i >> 5, b = i & 31;
    int id = (k == 0) ? 1 : tgt[b*100 + (k-1)];
    cur_ids[i] = (id >= 50000) ? 3 : id;
  }
  if (i < fEnd) flags[i] = 0u;
}

// ---------------- W1cT[q*56+g] = W1[g][196+q] ----------------
__global__ void w1c_transpose(const float* __restrict__ W1, float* __restrict__ W1cT){
  int i = blockIdx.x*256 + threadIdx.x;
  if (i < 17920){ int q = i / 56, g = i - q*56; W1cT[q*56+g] = W1[(size_t)g*516 + 196 + q]; }
}

// ------- rowgemm (emb gather): out[r][g] = sum_k emb[gid[r]][k]*W[g][k]+b1+b2 ---
struct RGArgs{ const int* gid; const float* emb; const float* W;
               const float* bias1; const float* bias2; float* out; int N; };
__global__ void __launch_bounds__(256) rowgemm(RGArgs a){
  __shared__ float rl[8*128];
  const int tid = threadIdx.x;
  const int N = a.N;
  const size_t r0 = (size_t)blockIdx.x*8;
  for (int i = tid; i < 8*128; i += 256){
    int r = i >> 7, k = i & 127;
    rl[i] = a.emb[(size_t)a.gid[r0+r]*128 + k];
  }
  __syncthreads();
  for (int g = tid; g < N; g += 256){
    const float* wr = a.W + (size_t)g*128;
    float acc[8];
    #pragma unroll
    for (int r=0;r<8;r++) acc[r]=0.f;
    for (int k=0;k<128;k+=4){
      float4 wv = *(const float4*)(wr+k);
      #pragma unroll
      for (int r=0;r<8;r++){
        float4 xv = *(const float4*)(rl + r*128 + k);
        acc[r] += wv.x*xv.x + wv.y*xv.y + wv.z*xv.z + wv.w*xv.w;
      }
    }
    float bias = a.bias1[g] + a.bias2[g];
    #pragma unroll
    for (int r=0;r<8;r++) a.out[(r0+r)*(size_t)N + g] = acc[r] + bias;
  }
}

// ---------------- es[r] = emb[gid[r]] . Wes ----------------
__global__ void es_kernel(const int* __restrict__ gid, const float* __restrict__ emb,
                          const float* __restrict__ Wes, float* __restrict__ es){
  int r = blockIdx.x, l = threadIdx.x;
  const float* e = emb + (size_t)gid[r]*128;
  float acc = e[l]*Wes[l] + e[l+64]*Wes[l+64];
  #pragma unroll
  for (int o=32;o;o>>=1) acc += __shfl_down(acc,o);
  if (l==0) es[r] = acc;
}

// ---------- encoder bidirectional LSTM (cooperative, 40 WGs, mask flags) -------
struct EncArgs{ const float* Xf; const float* Xb; const float* Whf; const float* Whb;
                float* hencB; float* cT; unsigned* flg; };
__global__ void __launch_bounds__(256) enc_scan(EncArgs a){
  extern __shared__ float sm[];
  float* Wl = sm;           // 5120
  float* hl = sm + 5120;    // 32 x 164
  const int wg = blockIdx.x;
  const int dir = wg/20, jwg = wg%20;
  const int tid = threadIdx.x;
  const int b = tid & 31, jl = tid >> 5;
  const int j = jwg*8 + jl;
  const float* Wh = dir ? a.Whb : a.Whf;
  const float* X  = dir ? a.Xb  : a.Xf;
  float* HB = a.hencB + (size_t)dir*32*256*160;
  for (int i = tid; i < 32*160; i += 256){
    int row = i/160, k = i - row*160;
    int gate = row >> 3, jj = row & 7;
    Wl[i] = Wh[((size_t)(gate*160 + jwg*8 + jj))*160 + k];
  }
  for (int i = tid; i < 32*164; i += 256) hl[i] = 0.f;
  float c = 0.f;
  const float4* w0 = (const float4*)(Wl + (0*8+jl)*160);
  const float4* w1 = (const float4*)(Wl + (1*8+jl)*160);
  const float4* w2 = (const float4*)(Wl + (2*8+jl)*160);
  const float4* w3 = (const float4*)(Wl + (3*8+jl)*160);
  __syncthreads();
  for (int t = 0; t < 256; ++t){
    const int trow = dir ? 255 - t : t;
    const float* xr = X + ((size_t)trow*32 + b)*640 + j;
    float g0 = xr[0], g1 = xr[160], g2 = xr[320], g3 = xr[480];
    if (t > 0){
      wait_mask<2>(a.flg + ENCW(dir, t-1), ENC_FULL, tid);
      const int tprev = dir ? (256 - t) : (t-1);
      for (int i2 = tid; i2 < 2560; i2 += 256){
        int bb = i2/80, kk = (i2 - bb*80)*2;
        float2 v = aload2(HB + ((size_t)bb*256 + tprev)*160 + kk);
        *(float2*)(hl + bb*164 + kk) = v;
      }
    }
    __syncthreads();
    const float4* hr = (const float4*)(hl + b*164);
    #pragma unroll 4
    for (int q = 0; q < 40; ++q){
      float4 hv = hr[q];
      float4 a0 = w0[q], a1 = w1[q], a2 = w2[q], a3 = w3[q];
      g0 += hv.x*a0.x + hv.y*a0.y + hv.z*a0.z + hv.w*a0.w;
      g1 += hv.x*a1.x + hv.y*a1.y + hv.z*a1.z + hv.w*a1.w;
      g2 += hv.x*a2.x + hv.y*a2.y + hv.z*a2.z + hv.w*a2.w;
      g3 += hv.x*a3.x + hv.y*a3.y + hv.z*a3.z + hv.w*a3.w;
    }
    float ig = sigm(g0), fg = sigm(g1), gc = fast_tanh(g2), og = sigm(g3);
    c = fg*c + ig*gc;
    float h = og * fast_tanh(c);
    astore(&HB[((size_t)b*256 + trow)*160 + j], h);
    __syncthreads();                       // drain vmcnt: h at LLC
    if (tid == 0) or_bit(a.flg + ENCW(dir, t), 1u << jwg);
  }
  a.cT[dir*5120 + b*160 + j] = c;
}

// ---------------- mid: h0/c0 projections ----------------
__global__ void mid_kernel(const float* __restrict__ hencB, const float* __restrict__ cT,
                           const float* __restrict__ Weh, const float* __restrict__ beh,
                           const float* __restrict__ Wec, const float* __restrict__ bec,
                           float* __restrict__ h0, float* __restrict__ c0){
  __shared__ float hc[320], cc[320];
  int b = blockIdx.x, tid = threadIdx.x;
  if (tid < 160){
    hc[tid]     = hencB[((size_t)b*256 + 255)*160 + tid];
    hc[160+tid] = hencB[((size_t)(32+b)*256 + 0)*160 + tid];
    cc[tid]     = cT[b*160 + tid];
    cc[160+tid] = cT[5120 + b*160 + tid];
  }
  __syncthreads();
  for (int g = tid; g < 196; g += 256){
    const float* w1 = Weh + (size_t)g*320;
    const float* w2 = Wec + (size_t)g*320;
    float a1 = beh[g], a2 = bec[g];
    for (int k = 0; k < 320; ++k){ a1 += hc[k]*w1[k]; a2 += cc[k]*w2[k]; }
    h0[b*196 + g] = a1;
    c0[b*196 + g] = a2;
  }
}

// ---------------- encA = [hf;hb] @ Wea.T + bea ----------------
__global__ void __launch_bounds__(256) encA_gemm(const float* __restrict__ hencB,
                 const float* __restrict__ Wea, const float* __restrict__ bea,
                 float* __restrict__ encA){
  __shared__ float rl[8*320];
  const int tid = threadIdx.x;
  const size_t r0 = (size_t)blockIdx.x*8;
  for (int i = tid; i < 8*320; i += 256){
    int r = i/320, k = i - r*320;
    size_t row = r0 + r; int b = (int)(row >> 8), t = (int)(row & 255);
    rl[i] = (k < 160) ? hencB[((size_t)b*256 + t)*160 + k]
                      : hencB[((size_t)(32+b)*256 + t)*160 + (k-160)];
  }
  __syncthreads();
  for (int g = tid; g < 224; g += 256){
    const float* wr = Wea + (size_t)g*320;
    float acc[8];
    #pragma unroll
    for (int r=0;r<8;r++) acc[r]=0.f;
    for (int k=0;k<320;k+=4){
      float4 wv = *(const float4*)(wr+k);
      #pragma unroll
      for (int r=0;r<8;r++){
        float4 xv = *(const float4*)(rl + r*320 + k);
        acc[r] += wv.x*xv.x + wv.y*xv.y + wv.z*xv.z + wv.w*xv.w;
      }
    }
    float bias = bea[g];
    #pragma unroll
    for (int r=0;r<8;r++) encA[(r0+r)*224 + g] = acc[r] + bias;
  }
}

// ---------------- decoder pipeline (cooperative, grid=281) ----------------
struct DecArgs{
  const float* Xd; const float* hencB; const float* encA;
  const float* h0; const float* c0;
  const float* Whd; const float* Wda; const float* Wca; const float* vat;
  const float* W1; const float* b1; const float* W1cT; const float* W2; const float* b2;
  const float* Wcs; const float* bcs; const float* Wds; const float* es;
  const int* in_ids; const int* tgt;
  float* hdAll; float* uAll; float* uPreAll; float* hwdaAll;
  float* hWdsAll; float* ctxWAll; float* copyAll;
  float* zidxAll; float* partAll; float* clAll; float* nllWg; float* out;
  unsigned* flg;
};

__global__ void __launch_bounds__(256) dec_scan(DecArgs A){
  extern __shared__ float sm[];
  const int wg = blockIdx.x, tid = threadIdx.x;
  const int bp = tid & 31, jl = tid >> 5;

  if (wg >= 256){
    // ======== LSTM producers (25 WGs): gates + h, then aux projections ========
    const int wl = wg - 256;
    const int j = wl*8 + jl;
    float* Wl   = sm;            // 6272
    float* scr  = sm + 6272;     // 32 x 204 = 6528
    float* wdaL = sm + 12800;    // 9 x 196 = 1764
    float* w1hL = sm + 14564;    // 3 x 196 = 588
    const int na = (wl == 24) ? 8 : 9;
    const int ng = (wl < 6) ? 3 : 2;
    for (int i = tid; i < 32*196; i += 256){
      int row = i/196, k = i - row*196;
      int gate = row >> 3, jj = row & 7;
      int jg = wl*8 + jj;
      Wl[i] = (jg < 196) ? A.Whd[((size_t)(gate*196 + jg))*196 + k] : 0.f;
    }
    for (int i = tid; i < na*196; i += 256){
      int al = i/196, k = i - al*196;
      wdaL[i] = A.Wda[(size_t)(wl*9 + al)*196 + k];
    }
    for (int i = tid; i < ng*196; i += 256){
      int gl = i/196, k = i - gl*196;
      w1hL[i] = A.W1[(size_t)(wl + 25*gl)*516 + k];
    }
    float c = (j < 196) ? A.c0[bp*196 + j] : 0.f;
    for (int i = tid; i < 6272; i += 256){
      int bb = i/196, k = i - bb*196;
      scr[bb*204 + k] = A.h0[i];
    }
    const float4* w0 = (const float4*)(Wl + (0*8+jl)*196);
    const float4* w1 = (const float4*)(Wl + (1*8+jl)*196);
    const float4* w2 = (const float4*)(Wl + (2*8+jl)*196);
    const float4* w3 = (const float4*)(Wl + (3*8+jl)*196);
    __syncthreads();
    for (int s = 0; s < 100; ++s){
      if (j < 196){
        const float* xr = A.Xd + ((size_t)s*32 + bp)*784 + j;
        float g0 = xr[0], g1 = xr[196], g2 = xr[392], g3 = xr[588];
        const float4* hr = (const float4*)(scr + bp*204);
        #pragma unroll 7
        for (int q = 0; q < 49; ++q){
          float4 hv = hr[q];
          float4 a0 = w0[q], a1 = w1[q], a2 = w2[q], a3 = w3[q];
          g0 += hv.x*a0.x + hv.y*a0.y + hv.z*a0.z + hv.w*a0.w;
          g1 += hv.x*a1.x + hv.y*a1.y + hv.z*a1.z + hv.w*a1.w;
          g2 += hv.x*a2.x + hv.y*a2.y + hv.z*a2.z + hv.w*a2.w;
          g3 += hv.x*a3.x + hv.y*a3.y + hv.z*a3.z + hv.w*a3.w;
        }
        float ig = sigm(g0), fg = sigm(g1), gc = fast_tanh(g2), og = sigm(g3);
        c = fg*c + ig*gc;
        float h = og * fast_tanh(c);
        astore(&A.hdAll[(size_t)s*6272 + bp*196 + j], h);
      }
      __syncthreads();               // drain: h parts at LLC
      if (tid == 0) or_bit(A.flg + FLSTM(s), 1u << wl);
      wait_mask<2>(A.flg + FLSTM(s), LSTM_FULL, tid);
      {
        const float* hp = A.hdAll + (size_t)s*6272;
        for (int i2 = tid; i2 < 3136; i2 += 256){
          float2 hv2 = aload2(hp + i2*2);
          int bb = i2/98, kk = (i2 - bb*98)*2;
          *(float2*)(scr + bb*204 + kk) = hv2;
        }
      }
      __syncthreads();
      // ---- aux(s): hwda rows, uPre rows, hWds ----
      for (int i = tid; i < na*32; i += 256){
        int al = i >> 5, bb = i & 31;
        const float4* h4 = (const float4*)(scr + bb*204);
        const float4* w4 = (const float4*)(wdaL + al*196);
        float acc = 0.f;
        #pragma unroll 7
        for (int q = 0; q < 49; ++q){
          float4 a4 = h4[q], b4 = w4[q];
          acc += a4.x*b4.x + a4.y*b4.y + a4.z*b4.z + a4.w*b4.w;
        }
        astore(&A.hwdaAll[(size_t)s*7168 + bb*224 + wl*9 + al], acc);
      }
      for (int i = tid; i < ng*32; i += 256){
        int gl = i >> 5, bb = i & 31;
        int g = wl + 25*gl;
        const float4* h4 = (const float4*)(scr + bb*204);
        const float4* w4 = (const float4*)(w1hL + gl*196);
        float acc = A.b1[g];
        #pragma unroll 7
        for (int q = 0; q < 49; ++q){
          float4 a4 = h4[q], b4 = w4[q];
          acc += a4.x*b4.x + a4.y*b4.y + a4.z*b4.z + a4.w*b4.w;
        }
        astore(&A.uPreAll[(size_t)s*1792 + bb*56 + g], acc);
      }
      if (wl == 24 && tid < 32){
        const float* hb = scr + tid*204;
        float acc = 0.f;
        #pragma unroll 4
        for (int q = 0; q < 196; ++q) acc += hb[q]*A.Wds[q];
        astore(&A.hWdsAll[s*32 + tid], acc);
      }
      __syncthreads();               // drain: aux at LLC
      if (tid == 0) or_bit(A.flg + FAUX(s), 1u << wl);
    }
    return;
  }

  if (wg < 32){
    // ======== P2: attention + ctx + u (32 WGs, b = wg) ========
    const int b = wg;
    float* hwdaL = sm;           // 224
    float* attnL = sm + 224;     // 256
    float* pctx  = sm + 480;     // 960
    float* ctxL  = sm + 1440;    // 320
    float* red   = sm + 1760;    // 4
    float* pu    = sm + 1764;    // 224
    float* wcaL  = sm + 1988;    // 224
    float* vL    = sm + 2212;    // 224
    float* WcsL  = sm + 2436;    // 320
    if (tid < 224){ wcaL[tid] = A.Wca[tid]; vL[tid] = A.vat[tid]; }
    for (int i = tid; i < 320; i += 256) WcsL[i] = A.Wcs[i];
    const int inid = A.in_ids[b*256 + tid];
    const float4* erow = (const float4*)(A.encA + (size_t)(b*256 + tid)*224);
    float cov = 0.f, clr = 0.f;
    __syncthreads();
    for (int s = 0; s < 100; ++s){
      wait_mask<2>(A.flg + FAUX(s), LSTM_FULL, tid);
      if (tid < 224) hwdaL[tid] = aload(&A.hwdaAll[(size_t)s*7168 + b*224 + tid]);
      __syncthreads();
      float exv = 0.f;
      if (inid != 0){
        float acc = 0.f;
        #pragma unroll 8
        for (int q = 0; q < 56; ++q){
          float4 ev = erow[q]; int a0 = 4*q;
          acc += fast_tanh(ev.x + hwdaL[a0]   + cov*wcaL[a0]  )*vL[a0];
          acc += fast_tanh(ev.y + hwdaL[a0+1] + cov*wcaL[a0+1])*vL[a0+1];
          acc += fast_tanh(ev.z + hwdaL[a0+2] + cov*wcaL[a0+2])*vL[a0+2];
          acc += fast_tanh(ev.w + hwdaL[a0+3] + cov*wcaL[a0+3])*vL[a0+3];
        }
        exv = __expf(acc);
      }
      float S = block_sum(exv, red);
      float attn = exv * __builtin_amdgcn_rcpf(S);
      attnL[tid] = attn;
      const int ntb = A.tgt[b*100 + s];
      float cpS = block_sum((inid == ntb) ? attn : 0.f, red);
      float mnS = block_sum(fminf(attn, cov), red);
      if (tid == 0){
        astore(&A.copyAll[s*32 + b], cpS);
        clr += mnS;
        if (s == 99) astore(&A.clAll[b], clr);
      }
      cov += attn;
      // ---- ctx from hencB ([b][t][160] rows, contiguous) ----
      if (tid < 240){
        int seg = tid/80, h4i = tid - seg*80;
        int t0 = seg*86, t1 = (t0+86 < 256) ? t0+86 : 256;
        const float* base = (h4i < 40)
          ? (A.hencB + ((size_t)b*256)*160 + (size_t)h4i*4)
          : (A.hencB + ((size_t)(32+b)*256)*160 + (size_t)(h4i-40)*4);
        float4 accv = {0.f,0.f,0.f,0.f};
        #pragma unroll 4
        for (int t2 = t0; t2 < t1; ++t2){
          float av = attnL[t2];
          float4 ev = *(const float4*)(base + (size_t)t2*160);
          accv.x += av*ev.x; accv.y += av*ev.y; accv.z += av*ev.z; accv.w += av*ev.w;
        }
        *(float4*)(pctx + (seg*80+h4i)*4) = accv;
      }
      __syncthreads();
      if (tid < 80){
        float4 p0 = *(float4*)(pctx + tid*4);
        float4 p1 = *(float4*)(pctx + (80+tid)*4);
        float4 p2v = *(float4*)(pctx + (160+tid)*4);
        float4 cvv;
        cvv.x = p0.x+p1.x+p2v.x; cvv.y = p0.y+p1.y+p2v.y;
        cvv.z = p0.z+p1.z+p2v.z; cvv.w = p0.w+p1.w+p2v.w;
        *(float4*)(ctxL + tid*4) = cvv;
      }
      __syncthreads();
      // ---- u (ctx part via W1cT, coalesced) + ctxWcs ----
      if (tid < 224){
        int g = tid % 56, seg = tid / 56;
        float acc = 0.f;
        const float* wp = A.W1cT + (size_t)seg*80*56 + g;
        #pragma unroll 4
        for (int q = 0; q < 80; ++q) acc += ctxL[seg*80 + q] * wp[q*56];
        pu[seg*56 + g] = acc;
      } else {
        int l = tid - 224; float acc = 0.f;
        for (int q = l; q < 320; q += 32) acc += ctxL[q]*WcsL[q];
        #pragma unroll
        for (int o=16;o;o>>=1) acc += __shfl_down(acc,o,32);
        if (l==0) astore(&A.ctxWAll[s*32 + b], acc);
      }
      __syncthreads();
      if (tid < 56){
        float upre = aload(&A.uPreAll[(size_t)s*1792 + b*56 + tid]);
        float uu = fast_tanh(upre + pu[tid] + pu[56+tid] + pu[112+tid] + pu[168+tid]);
        astore(&A.uAll[(size_t)s*1792 + b*56 + tid], uu);
      }
      __syncthreads();               // drain: u/scalars at LLC
      if (tid == 0){
        or_bit(A.flg + FP2W(s,0), 1u << b);
        or_bit(A.flg + FP2W(s,1), 1u << b);
        or_bit(A.flg + FP2W(s,2), 1u << b);
        or_bit(A.flg + FP2W(s,3), 1u << b);
      }
    }
    return;
  }

  // ======== P3: vocab sum-exp, W2 rows pinned in registers (224 WGs) ========
  {
    const int wgv = wg - 32;
    const int vs = (wgv*49998)/224, ve = ((wgv+1)*49998)/224;
    const int v = vs + tid;
    const bool valid = v < ve;
    const int vc = valid ? v : 0;
    float4 w2r[14];
    {
      const float4* wr = (const float4*)(A.W2 + (size_t)vc*56);
      #pragma unroll
      for (int q=0;q<14;++q) w2r[q] = wr[q];
    }
    const float b2v = A.b2[vc];
    float* ulL  = sm;                  // 1792
    float* redW = sm + 1792;           // 128
    int*   idxL = (int*)(sm + 1920);   // 32
    float* red  = sm + 1952;           // 4
    const int lane = tid & 63, wv2 = tid >> 6;
    for (int s = 0; s < 100; ++s){
      int nt3 = (tid < 32) ? A.tgt[tid*100 + s] : 0;
      wait_mask<8>(A.flg + FP2W(s, wgv & 3), P2_FULL, tid);
      for (int i2 = tid; i2 < 896; i2 += 256){
        float2 u2 = aload2(&A.uAll[(size_t)s*1792 + i2*2]);
        *(float2*)(ulL + i2*2) = u2;
      }
      if (tid < 32){
        int ix = nt3 - 2; ix = ix<0?0:(ix>49997?49997:ix);
        idxL[tid] = ix;
      }
      __syncthreads();
      #pragma unroll 4
      for (int bb=0; bb<32; ++bb){
        const float4* uv = (const float4*)(ulL + bb*56);
        float z = b2v;
        #pragma unroll
        for (int q=0;q<14;++q){
          float4 u4 = uv[q];
          z += w2r[q].x*u4.x + w2r[q].y*u4.y + w2r[q].z*u4.z + w2r[q].w*u4.w;
        }
        if (valid && v == idxL[bb]) astore(&A.zidxAll[s*32+bb], z);
        float sv2 = valid ? __expf(z) : 0.f;
        #pragma unroll
        for (int o=32;o;o>>=1) sv2 += __shfl_down(sv2,o);
        if (lane == 0) redW[wv2*32+bb] = sv2;
      }
      __syncthreads();
      if (tid < 32){
        float tot = redW[tid]+redW[32+tid]+redW[64+tid]+redW[96+tid];
        astore(&A.partAll[(size_t)(s*32+tid)*224 + wgv], tot);
      }
      __syncthreads();
    }
    __syncthreads();
    if (tid == 0) add1(A.flg + CP3);
    // ---- finalize stage 1 ----
    if (tid == 0){
      while (__hip_atomic_load(A.flg + CP3, __ATOMIC_RELAXED, MSCOPE) != 224u)
        __builtin_amdgcn_s_sleep(32);
    }
    __syncthreads();
    float nll1 = 0.f;
    for (int p = wgv; p < 3200; p += 224){
      float pv = (tid < 224) ? aload(&A.partAll[(size_t)p*224 + tid]) : 0.f;
      float se = block_sum(pv, red);
      if (tid == 0){
        int s = p >> 5, b = p & 31;
        int nt2 = A.tgt[b*100 + s];
        float xg = aload(&A.ctxWAll[p]) + A.bcs[0] + aload(&A.hWdsAll[p]) + A.es[p];
        float pg = 1.f/(1.f + __expf(-xg));
        float genp = (nt2 >= 2 && nt2 < 50000) ? (__expf(aload(&A.zidxAll[p])) / se) : 0.f;
        float pr = pg*genp + (1.f-pg)*aload(&A.copyAll[p]);
        nll1 += -logf(pr + 1e-9f);
      }
    }
    if (tid == 0) astore(&A.nllWg[wgv], nll1);
    __syncthreads();
    if (tid == 0) add1(A.flg + CFIN);
    // ---- finalize stage 2 (one WG) ----
    if (wg == 32){
      if (tid == 0){
        while (__hip_atomic_load(A.flg + CFIN, __ATOMIC_RELAXED, MSCOPE) != 224u)
          __builtin_amdgcn_s_sleep(32);
      }
      __syncthreads();
      float nv = (tid < 224) ? aload(&A.nllWg[tid]) : 0.f;
      float nll = block_sum(nv, red);
      float cv = (tid < 32) ? aload(&A.clAll[tid]) : 0.f;
      float cl = block_sum(cv, red);
      if (tid == 0){ A.out[0]=nll; A.out[1]=cl; A.out[2]=nll + 0.75f*cl; }
    }
  }
}

// ---------------- host launch ----------------
extern "C" void kernel_launch(void* const* d_in, const int* in_sizes, int n_in,
                              void* d_out, int out_size, void* d_ws, size_t ws_size,
                              hipStream_t stream){
  const int*   in_ids = (const int*)  d_in[0];
  const int*   tgt    = (const int*)  d_in[1];
  const float* emb    = (const float*)d_in[3];
  const float* Wi_f   = (const float*)d_in[4];
  const float* Wh_f   = (const float*)d_in[5];
  const float* bi_f   = (const float*)d_in[6];
  const float* bh_f   = (const float*)d_in[7];
  const float* Wi_b   = (const float*)d_in[8];
  const float* Wh_b   = (const float*)d_in[9];
  const float* bi_b   = (const float*)d_in[10];
  const float* bh_b   = (const float*)d_in[11];
  const float* Weh    = (const float*)d_in[12];
  const float* beh    = (const float*)d_in[13];
  const float* Wec    = (const float*)d_in[14];
  const float* bec    = (const float*)d_in[15];
  const float* Wi_d   = (const float*)d_in[16];
  const float* Wh_d   = (const float*)d_in[17];
  const float* bi_d   = (const float*)d_in[18];
  const float* bh_d   = (const float*)d_in[19];
  const float* Wea    = (const float*)d_in[20];
  const float* bea    = (const float*)d_in[21];
  const float* Wda    = (const float*)d_in[22];
  const float* Wca    = (const float*)d_in[23];
  const float* vat    = (const float*)d_in[24];
  const float* W1     = (const float*)d_in[25];
  const float* b1     = (const float*)d_in[26];
  const float* W2     = (const float*)d_in[27];
  const float* b2     = (const float*)d_in[28];
  const float* Wcs    = (const float*)d_in[29];
  const float* bcs    = (const float*)d_in[30];
  const float* Wds    = (const float*)d_in[31];
  const float* Wes    = (const float*)d_in[32];

  float* ws = (float*)d_ws;
  int* iBase = (int*)(ws + oFEnd);
  int* in_mapped = iBase;
  int* cur_ids   = iBase + 8192;
  unsigned* flags = (unsigned*)(iBase + 11392);

  prep_kernel<<<128, 256, 0, stream>>>(in_ids, tgt, in_mapped, cur_ids, flags);
  w1c_transpose<<<70, 256, 0, stream>>>(W1, ws + oW1cT);

  { RGArgs a{in_mapped, emb, Wi_f, bi_f, bh_f, ws + oXf, 640};
    rowgemm<<<1024, 256, 0, stream>>>(a); }
  { RGArgs a{in_mapped, emb, Wi_b, bi_b, bh_b, ws + oXb, 640};
    rowgemm<<<1024, 256, 0, stream>>>(a); }
  { RGArgs a{cur_ids, emb, Wi_d, bi_d, bh_d, ws + oXd, 784};
    rowgemm<<<400, 256, 0, stream>>>(a); }

  es_kernel<<<3200, 64, 0, stream>>>(cur_ids, emb, Wes, ws + oEs);

  { EncArgs ea{ws + oXf, ws + oXb, Wh_f, Wh_b, ws + oHencB, ws + oCT,
               flags};
    void* ka[] = {&ea};
    hipLaunchCooperativeKernel((void*)enc_scan, dim3(40), dim3(256), ka,
                               (unsigned)((5120 + 32*164)*4), stream); }

  mid_kernel<<<32, 256, 0, stream>>>(ws + oHencB, ws + oCT, Weh, beh, Wec, bec,
                                     ws + oH0, ws + oC0);

  encA_gemm<<<1024, 256, 0, stream>>>(ws + oHencB, Wea, bea, ws + oEncA);

  { DecArgs da{ws + oXd, ws + oHencB, ws + oEncA,
               ws + oH0, ws + oC0,
               Wh_d, Wda, Wca, vat,
               W1, b1, ws + oW1cT, W2, b2, Wcs, bcs, Wds, ws + oEs,
               in_ids, tgt,
               ws + oHdAll, ws + oUAll, ws + oUPreAll, ws + oHwdaAll,
               ws + oHWdsAll, ws + oCtxWAll, ws + oCopyAll,
               ws + oZidxAll, ws + oPartAll, ws + oClAll, ws + oNllWg, (float*)d_out,
               flags};
    void* ka[] = {&da};
    hipLaunchCooperativeKernel((void*)dec_scan, dim3(281), dim3(256), ka,
                               (unsigned)(15152*4), stream); }
}

// Round 8
// 4650.504 us; speedup vs baseline: 1.9148x; 1.0875x over previous
//
#include <hip/hip_runtime.h>

#define MSCOPE __HIP_MEMORY_SCOPE_AGENT

// ---------------- model dims ----------------
// V=50000 E=128 H=160 D=196 A=224 BN=56, B=32, Tin=256, Ttgt=100
// X layouts (TRANSPOSED): Xf/Xb = [t][640][32], Xd = [s][784][32]
// hencB layout: [dir*32+b][t][160];  hdAll exchange: [s][196][32] (j-major)

// ---------------- ws float layout ----------------
constexpr size_t oXf   = 0;                                // 256 x 640 x 32
constexpr size_t oXb   = oXf   + (size_t)8192*640;
constexpr size_t oXd   = oXb   + (size_t)8192*640;         // 100 x 784 x 32
constexpr size_t oHencB= oXd   + (size_t)3200*784;         // 64 x 256 x 160
constexpr size_t oEncA = oHencB+ (size_t)64*256*160;       // 8192 x 224
constexpr size_t oEs   = oEncA + (size_t)8192*224;         // 3200
constexpr size_t oCT   = oEs   + 3200;                     // 2 x 5120
constexpr size_t oH0   = oCT   + 10240;                    // 32 x 196
constexpr size_t oC0   = oH0   + 6272;                     // 32 x 196
constexpr size_t oHWdsAll = oC0 + 6272;                    // 100 x 32
constexpr size_t oCtxWAll = oHWdsAll + 3200;
constexpr size_t oCopyAll = oCtxWAll + 3200;
constexpr size_t oZidxAll = oCopyAll + 3200;
constexpr size_t oClAll   = oZidxAll + 3200;               // 32
constexpr size_t oNllWg   = oClAll + 32;                   // 224
constexpr size_t oW1cT    = oNllWg + 224;                  // 320 x 56
constexpr size_t oFEnd    = oW1cT + 17920;
// dec-phase overlays on the (dead) Xf region:
constexpr size_t oHdAll   = 0;                             // 100 x 196 x 32
constexpr size_t oUAll    = oHdAll + (size_t)100*6272;     // 100 x 1792
constexpr size_t oUPreAll = oUAll  + (size_t)100*1792;     // 100 x 1792
constexpr size_t oHwdaAll = oUPreAll + (size_t)100*1792;   // 100 x 32 x 224
constexpr size_t oPartAll = oHwdaAll + (size_t)100*7168;   // 100 x 32 x 224
// ints after floats: in_mapped[8192], cur_ids[3200], flags[17800]
#define ENCW(d,t)  (((d)*256 + (t))*16)
#define FLSTM(s)   (8192 + (s)*16)
#define FAUX(s)    (9792 + (s)*16)
#define FP2W(s,m)  (11392 + (s)*64 + (m)*16)
#define CP3        17792
#define CFIN       17793
constexpr int fEnd = 17800;
constexpr unsigned ENC_FULL  = 0xFFFFFu;     // 20 bits
constexpr unsigned LSTM_FULL = 0x1FFFFFFu;   // 25 bits
constexpr unsigned AUX_FULL  = 0xFFu;        // 8 bits
constexpr unsigned P2_FULL   = 0xFFFFFFFFu;  // 32 bits

// ---------------- helpers ----------------
__device__ __forceinline__ float fast_tanh(float x){
  float e = __expf(-2.f*fabsf(x));
  float r = (1.f - e) * __builtin_amdgcn_rcpf(1.f + e);
  return copysignf(r, x);
}
__device__ __forceinline__ float sigm(float x){
  return __builtin_amdgcn_rcpf(1.f + __expf(-x));
}
// relaxed agent-scope: LLC-coherent, no L2 wb/inv
__device__ __forceinline__ float aload(const float* p){
  return __hip_atomic_load(const_cast<float*>(p), __ATOMIC_RELAXED, MSCOPE);
}
__device__ __forceinline__ float2 aload2(const float* p){
  unsigned long long u = __hip_atomic_load(
      reinterpret_cast<unsigned long long*>(const_cast<float*>(p)),
      __ATOMIC_RELAXED, MSCOPE);
  float2 r; __builtin_memcpy(&r, &u, 8); return r;
}
__device__ __forceinline__ void astore(float* p, float v){
  __hip_atomic_store(p, v, __ATOMIC_RELAXED, MSCOPE);
}
// single-lane poll of one mask word; others park at barrier (no poll storm)
template<int SLP>
__device__ __forceinline__ void wait_mask(unsigned* word, unsigned target, int tid){
  if (tid == 0){
    while (__hip_atomic_load(word, __ATOMIC_RELAXED, MSCOPE) != target)
      __builtin_amdgcn_s_sleep(SLP);
  }
  __syncthreads();
}
// producers: __syncthreads() (drains vmcnt -> data ack'd at LLC) BEFORE or_bit
__device__ __forceinline__ void or_bit(unsigned* word, unsigned bit){
  (void)__hip_atomic_fetch_or(word, bit, __ATOMIC_RELAXED, MSCOPE);
}
__device__ __forceinline__ void add1(unsigned* word){
  (void)__hip_atomic_fetch_add(word, 1u, __ATOMIC_RELAXED, MSCOPE);
}
__device__ __forceinline__ float block_sum(float v, float* red){
  #pragma unroll
  for (int o=32;o;o>>=1) v += __shfl_down(v,o);
  if ((threadIdx.x&63)==0) red[threadIdx.x>>6] = v;
  __syncthreads();
  v = red[0]+red[1]+red[2]+red[3];
  __syncthreads();
  return v;
}

// ---------------- prep: id mapping + flag zeroing ----------------
__global__ void prep_kernel(const int* __restrict__ in_ids, const int* __restrict__ tgt,
                            int* __restrict__ in_mapped, int* __restrict__ cur_ids,
                            unsigned* __restrict__ flags){
  int i = blockIdx.x*256 + threadIdx.x;
  if (i < 8192){
    int t = i >> 5, b = i & 31;
    int id = in_ids[b*256 + t];
    in_mapped[i] = (id >= 50000) ? 3 : id;
  }
  if (i < 3200){
    int k = i >> 5, b = i & 31;
    int id = (k == 0) ? 1 : tgt[b*100 + (k-1)];
    cur_ids[i] = (id >= 50000) ? 3 : id;
  }
  if (i < fEnd) flags[i] = 0u;
}

// ---------------- W1cT[q*56+g] = W1[g][196+q] ----------------
__global__ void w1c_transpose(const float* __restrict__ W1, float* __restrict__ W1cT){
  int i = blockIdx.x*256 + threadIdx.x;
  if (i < 17920){ int q = i / 56, g = i - q*56; W1cT[q*56+g] = W1[(size_t)g*516 + 196 + q]; }
}

// ------- rowgemm: gather emb rows, write TRANSPOSED out[(t*N+g)*32+b] ---------
struct RGArgs{ const int* gid; const float* emb; const float* W;
               const float* bias1; const float* bias2; float* out; int N; };
__global__ void __launch_bounds__(256) rowgemm(RGArgs a){
  __shared__ float rl[8*128];
  const int tid = threadIdx.x;
  const int N = a.N;
  const size_t r0 = (size_t)blockIdx.x*8;
  const size_t t = r0 >> 5; const int b0 = (int)(r0 & 31);
  for (int i = tid; i < 8*128; i += 256){
    int r = i >> 7, k = i & 127;
    rl[i] = a.emb[(size_t)a.gid[r0+r]*128 + k];
  }
  __syncthreads();
  for (int g = tid; g < N; g += 256){
    const float* wr = a.W + (size_t)g*128;
    float acc[8];
    #pragma unroll
    for (int r=0;r<8;r++) acc[r]=0.f;
    for (int k=0;k<128;k+=4){
      float4 wv = *(const float4*)(wr+k);
      #pragma unroll
      for (int r=0;r<8;r++){
        float4 xv = *(const float4*)(rl + r*128 + k);
        acc[r] += wv.x*xv.x + wv.y*xv.y + wv.z*xv.z + wv.w*xv.w;
      }
    }
    float bias = a.bias1[g] + a.bias2[g];
    float* op = a.out + ((size_t)t*N + g)*32 + b0;
    *(float4*)(op)   = make_float4(acc[0]+bias,acc[1]+bias,acc[2]+bias,acc[3]+bias);
    *(float4*)(op+4) = make_float4(acc[4]+bias,acc[5]+bias,acc[6]+bias,acc[7]+bias);
  }
}

// ---------------- es[r] = emb[gid[r]] . Wes ----------------
__global__ void es_kernel(const int* __restrict__ gid, const float* __restrict__ emb,
                          const float* __restrict__ Wes, float* __restrict__ es){
  int r = blockIdx.x, l = threadIdx.x;
  const float* e = emb + (size_t)gid[r]*128;
  float acc = e[l]*Wes[l] + e[l+64]*Wes[l+64];
  #pragma unroll
  for (int o=32;o;o>>=1) acc += __shfl_down(acc,o);
  if (l==0) es[r] = acc;
}

// ---------- encoder bidirectional LSTM (cooperative, 40 WGs, mask flags) -------
struct EncArgs{ const float* Xf; const float* Xb; const float* Whf; const float* Whb;
                float* hencB; float* cT; unsigned* flg; };
__global__ void __launch_bounds__(256) enc_scan(EncArgs a){
  extern __shared__ float sm[];
  float* Wl = sm;           // 5120
  float* hl = sm + 5120;    // 32 x 164
  const int wg = blockIdx.x;
  const int dir = wg/20, jwg = wg%20;
  const int tid = threadIdx.x;
  const int b = tid & 31, jl = tid >> 5;
  const int j = jwg*8 + jl;
  const float* Wh = dir ? a.Whb : a.Whf;
  const float* X  = dir ? a.Xb  : a.Xf;
  float* HB = a.hencB + (size_t)dir*32*256*160;
  unsigned* flg = a.flg;
  for (int i = tid; i < 32*160; i += 256){
    int row = i/160, k = i - row*160;
    int gate = row >> 3, jj = row & 7;
    Wl[i] = Wh[((size_t)(gate*160 + jwg*8 + jj))*160 + k];
  }
  for (int i = tid; i < 32*164; i += 256) hl[i] = 0.f;
  float c = 0.f;
  const float4* w0 = (const float4*)(Wl + (0*8+jl)*160);
  const float4* w1 = (const float4*)(Wl + (1*8+jl)*160);
  const float4* w2 = (const float4*)(Wl + (2*8+jl)*160);
  const float4* w3 = (const float4*)(Wl + (3*8+jl)*160);
  __syncthreads();
  for (int t = 0; t < 256; ++t){
    const int trow = dir ? 255 - t : t;
    // X layout [t][g*160+j][b]: issue loads BEFORE the flag wait
    const float* xr = X + ((size_t)trow*640 + j)*32 + b;
    float g0 = xr[0], g1 = xr[5120], g2 = xr[10240], g3 = xr[15360];
    if (t > 0){
      wait_mask<2>(flg + ENCW(dir, t-1), ENC_FULL, tid);
      const int tprev = dir ? (256 - t) : (t-1);
      for (int i2 = tid; i2 < 2560; i2 += 256){
        int bb = i2/80, kk = (i2 - bb*80)*2;
        float2 v = aload2(HB + ((size_t)bb*256 + tprev)*160 + kk);
        *(float2*)(hl + bb*164 + kk) = v;
      }
    }
    __syncthreads();
    const float4* hr = (const float4*)(hl + b*164);
    #pragma unroll 4
    for (int q = 0; q < 40; ++q){
      float4 hv = hr[q];
      float4 a0 = w0[q], a1 = w1[q], a2 = w2[q], a3 = w3[q];
      g0 += hv.x*a0.x + hv.y*a0.y + hv.z*a0.z + hv.w*a0.w;
      g1 += hv.x*a1.x + hv.y*a1.y + hv.z*a1.z + hv.w*a1.w;
      g2 += hv.x*a2.x + hv.y*a2.y + hv.z*a2.z + hv.w*a2.w;
      g3 += hv.x*a3.x + hv.y*a3.y + hv.z*a3.z + hv.w*a3.w;
    }
    float ig = sigm(g0), fg = sigm(g1), gc = fast_tanh(g2), og = sigm(g3);
    c = fg*c + ig*gc;
    float h = og * fast_tanh(c);
    astore(&HB[((size_t)b*256 + trow)*160 + j], h);
    __syncthreads();                       // drain vmcnt: h at LLC
    if (tid == 0) or_bit(flg + ENCW(dir, t), 1u << jwg);
  }
  a.cT[dir*5120 + b*160 + j] = c;
}

// ---------------- mid: h0/c0 projections ----------------
__global__ void mid_kernel(const float* __restrict__ hencB, const float* __restrict__ cT,
                           const float* __restrict__ Weh, const float* __restrict__ beh,
                           const float* __restrict__ Wec, const float* __restrict__ bec,
                           float* __restrict__ h0, float* __restrict__ c0){
  __shared__ float hc[320], cc[320];
  int b = blockIdx.x, tid = threadIdx.x;
  if (tid < 160){
    hc[tid]     = hencB[((size_t)b*256 + 255)*160 + tid];
    hc[160+tid] = hencB[((size_t)(32+b)*256 + 0)*160 + tid];
    cc[tid]     = cT[b*160 + tid];
    cc[160+tid] = cT[5120 + b*160 + tid];
  }
  __syncthreads();
  for (int g = tid; g < 196; g += 256){
    const float* w1 = Weh + (size_t)g*320;
    const float* w2 = Wec + (size_t)g*320;
    float a1 = beh[g], a2 = bec[g];
    for (int k = 0; k < 320; ++k){ a1 += hc[k]*w1[k]; a2 += cc[k]*w2[k]; }
    h0[b*196 + g] = a1;
    c0[b*196 + g] = a2;
  }
}

// ---------------- encA = [hf;hb] @ Wea.T + bea ----------------
__global__ void __launch_bounds__(256) encA_gemm(const float* __restrict__ hencB,
                 const float* __restrict__ Wea, const float* __restrict__ bea,
                 float* __restrict__ encA){
  __shared__ float rl[8*320];
  const int tid = threadIdx.x;
  const size_t r0 = (size_t)blockIdx.x*8;
  for (int i = tid; i < 8*320; i += 256){
    int r = i/320, k = i - r*320;
    size_t row = r0 + r; int b = (int)(row >> 8), t = (int)(row & 255);
    rl[i] = (k < 160) ? hencB[((size_t)b*256 + t)*160 + k]
                      : hencB[((size_t)(32+b)*256 + t)*160 + (k-160)];
  }
  __syncthreads();
  for (int g = tid; g < 224; g += 256){
    const float* wr = Wea + (size_t)g*320;
    float acc[8];
    #pragma unroll
    for (int r=0;r<8;r++) acc[r]=0.f;
    for (int k=0;k<320;k+=4){
      float4 wv = *(const float4*)(wr+k);
      #pragma unroll
      for (int r=0;r<8;r++){
        float4 xv = *(const float4*)(rl + r*320 + k);
        acc[r] += wv.x*xv.x + wv.y*xv.y + wv.z*xv.z + wv.w*xv.w;
      }
    }
    float bias = bea[g];
    #pragma unroll
    for (int r=0;r<8;r++) encA[(r0+r)*224 + g] = acc[r] + bias;
  }
}

// ---------------- decoder pipeline (cooperative, grid=289) ----------------
// wg 0-24: LSTM | 25-32: aux | 33-64: P2 (b=wg-33) | 65-288: P3 (wgv=wg-65)
struct DecArgs{
  const float* Xd; const float* hencB; const float* encA;
  const float* h0; const float* c0;
  const float* Whd; const float* Wda; const float* Wca; const float* vat;
  const float* W1; const float* b1; const float* W1cT; const float* W2; const float* b2;
  const float* Wcs; const float* bcs; const float* Wds; const float* es;
  const int* in_ids; const int* tgt;
  float* hdAll; float* uAll; float* uPreAll; float* hwdaAll;
  float* hWdsAll; float* ctxWAll; float* copyAll;
  float* zidxAll; float* partAll; float* clAll; float* nllWg; float* out;
  unsigned* flg;
};

// load h(s) from j-major hdAll into scr[b*204+j]
__device__ __forceinline__ void load_scr(const float* hp, float* scr, int tid){
  for (int i2 = tid; i2 < 3136; i2 += 256){
    float2 hv = aload2(hp + i2*2);
    int e = i2*2; int b2 = e & 31; int j2 = e >> 5;
    scr[b2*204 + j2]     = hv.x;
    scr[(b2+1)*204 + j2] = hv.y;
  }
}

__global__ void __launch_bounds__(256) dec_scan(DecArgs A){
  extern __shared__ float sm[];
  const int wg = blockIdx.x, tid = threadIdx.x;
  const int bp = tid & 31, jl = tid >> 5;
  unsigned* flg = A.flg;

  if (wg < 25){
    // ======== LSTM chain (25 WGs): gates only, one flag per step ========
    const int wl = wg;
    const int j = wl*8 + jl;
    float* Wl  = sm;           // 6272
    float* scr = sm + 6272;    // 32 x 204 = 6528
    for (int i = tid; i < 32*196; i += 256){
      int row = i/196, k = i - row*196;
      int gate = row >> 3, jj = row & 7;
      int jg = wl*8 + jj;
      Wl[i] = (jg < 196) ? A.Whd[((size_t)(gate*196 + jg))*196 + k] : 0.f;
    }
    float c = (j < 196) ? A.c0[bp*196 + j] : 0.f;
    for (int i = tid; i < 6272; i += 256){
      int bb = i/196, k = i - bb*196;
      scr[bb*204 + k] = A.h0[i];
    }
    const float4* w0 = (const float4*)(Wl + (0*8+jl)*196);
    const float4* w1 = (const float4*)(Wl + (1*8+jl)*196);
    const float4* w2 = (const float4*)(Wl + (2*8+jl)*196);
    const float4* w3 = (const float4*)(Wl + (3*8+jl)*196);
    __syncthreads();
    for (int s = 0; s < 100; ++s){
      float x0=0.f,x1=0.f,x2=0.f,x3=0.f;
      if (j < 196){
        // Xd layout [s][g*196+j][b] — issue before the wait
        const float* xr = A.Xd + ((size_t)s*784 + j)*32 + bp;
        x0 = xr[0]; x1 = xr[6272]; x2 = xr[12544]; x3 = xr[18816];
      }
      if (s > 0){
        wait_mask<2>(flg + FLSTM(s-1), LSTM_FULL, tid);
        load_scr(A.hdAll + (size_t)(s-1)*6272, scr, tid);
      }
      __syncthreads();
      if (j < 196){
        float g0=x0,g1=x1,g2=x2,g3=x3;
        const float4* hr = (const float4*)(scr + bp*204);
        #pragma unroll 7
        for (int q = 0; q < 49; ++q){
          float4 hv = hr[q];
          float4 a0 = w0[q], a1 = w1[q], a2 = w2[q], a3 = w3[q];
          g0 += hv.x*a0.x + hv.y*a0.y + hv.z*a0.z + hv.w*a0.w;
          g1 += hv.x*a1.x + hv.y*a1.y + hv.z*a1.z + hv.w*a1.w;
          g2 += hv.x*a2.x + hv.y*a2.y + hv.z*a2.z + hv.w*a2.w;
          g3 += hv.x*a3.x + hv.y*a3.y + hv.z*a3.z + hv.w*a3.w;
        }
        float ig = sigm(g0), fg = sigm(g1), gc = fast_tanh(g2), og = sigm(g3);
        c = fg*c + ig*gc;
        float h = og * fast_tanh(c);
        astore(&A.hdAll[(size_t)s*6272 + j*32 + bp], h);   // [s][j][b]: coalesced
      }
      __syncthreads();               // drain: h at LLC (8 lines/WG)
      if (tid == 0) or_bit(flg + FLSTM(s), 1u << wl);
    }
    return;
  }

  if (wg < 33){
    // ======== aux stage (8 WGs): hwda / uPre / hWds off the LSTM chain ========
    const int a_ = wg - 25;
    float* wdaL = sm;            // 28*196 = 5488
    float* w1hL = sm + 5488;     // 7*196 = 1372
    float* WdsL = sm + 6860;     // 196
    float* scr  = sm + 7056;     // 6528
    for (int i = tid; i < 28*196; i += 256){
      int al = i/196, k = i - al*196;
      wdaL[i] = A.Wda[(size_t)(a_*28 + al)*196 + k];
    }
    for (int i = tid; i < 7*196; i += 256){
      int gl = i/196, k = i - gl*196;
      w1hL[i] = A.W1[(size_t)(a_*7 + gl)*516 + k];
    }
    if (a_ == 7) for (int i = tid; i < 196; i += 256) WdsL[i] = A.Wds[i];
    __syncthreads();
    for (int s = 0; s < 100; ++s){
      wait_mask<2>(flg + FLSTM(s), LSTM_FULL, tid);
      load_scr(A.hdAll + (size_t)s*6272, scr, tid);
      __syncthreads();
      for (int i = tid; i < 896; i += 256){
        int b2 = i & 31, al = i >> 5;
        const float4* h4 = (const float4*)(scr + b2*204);
        const float4* w4 = (const float4*)(wdaL + al*196);
        float acc = 0.f;
        #pragma unroll 7
        for (int q = 0; q < 49; ++q){
          float4 a4 = h4[q], b4 = w4[q];
          acc += a4.x*b4.x + a4.y*b4.y + a4.z*b4.z + a4.w*b4.w;
        }
        astore(&A.hwdaAll[(size_t)s*7168 + b2*224 + a_*28 + al], acc);
      }
      if (tid < 224){
        int b2 = tid & 31, gl = tid >> 5;
        int g = a_*7 + gl;
        const float4* h4 = (const float4*)(scr + b2*204);
        const float4* w4 = (const float4*)(w1hL + gl*196);
        float acc = A.b1[g];
        #pragma unroll 7
        for (int q = 0; q < 49; ++q){
          float4 a4 = h4[q], b4 = w4[q];
          acc += a4.x*b4.x + a4.y*b4.y + a4.z*b4.z + a4.w*b4.w;
        }
        astore(&A.uPreAll[(size_t)s*1792 + b2*56 + g], acc);
      }
      if (a_ == 7 && tid < 32){
        const float* hb = scr + tid*204;
        float acc = 0.f;
        #pragma unroll 4
        for (int q = 0; q < 196; ++q) acc += hb[q]*WdsL[q];
        astore(&A.hWdsAll[s*32 + tid], acc);
      }
      __syncthreads();               // drain: aux at LLC
      if (tid == 0) or_bit(flg + FAUX(s), 1u << a_);
    }
    return;
  }

  if (wg < 65){
    // ======== P2: attention + ctx + u (32 WGs, b = wg-33) ========
    const int b = wg - 33;
    float* hwdaL = sm;           // 224
    float* attnL = sm + 224;     // 256
    float* pctx  = sm + 480;     // 960
    float* ctxL  = sm + 1440;    // 320
    float* red   = sm + 1760;    // 4
    float* pu    = sm + 1764;    // 224
    float* wcaL  = sm + 1988;    // 224
    float* vL    = sm + 2212;    // 224
    float* WcsL  = sm + 2436;    // 320
    if (tid < 224){ wcaL[tid] = A.Wca[tid]; vL[tid] = A.vat[tid]; }
    for (int i = tid; i < 320; i += 256) WcsL[i] = A.Wcs[i];
    const int inid = A.in_ids[b*256 + tid];
    const float4* erow = (const float4*)(A.encA + (size_t)(b*256 + tid)*224);
    float cov = 0.f, clr = 0.f;
    __syncthreads();
    for (int s = 0; s < 100; ++s){
      wait_mask<2>(flg + FAUX(s), AUX_FULL, tid);
      if (tid < 224) hwdaL[tid] = aload(&A.hwdaAll[(size_t)s*7168 + b*224 + tid]);
      __syncthreads();
      float exv = 0.f;
      if (inid != 0){
        float acc = 0.f;
        #pragma unroll 8
        for (int q = 0; q < 56; ++q){
          float4 ev = erow[q]; int a0 = 4*q;
          acc += fast_tanh(ev.x + hwdaL[a0]   + cov*wcaL[a0]  )*vL[a0];
          acc += fast_tanh(ev.y + hwdaL[a0+1] + cov*wcaL[a0+1])*vL[a0+1];
          acc += fast_tanh(ev.z + hwdaL[a0+2] + cov*wcaL[a0+2])*vL[a0+2];
          acc += fast_tanh(ev.w + hwdaL[a0+3] + cov*wcaL[a0+3])*vL[a0+3];
        }
        exv = __expf(acc);
      }
      float S = block_sum(exv, red);
      float attn = exv * __builtin_amdgcn_rcpf(S);
      attnL[tid] = attn;
      const int ntb = A.tgt[b*100 + s];
      float cpS = block_sum((inid == ntb) ? attn : 0.f, red);
      float mnS = block_sum(fminf(attn, cov), red);
      if (tid == 0){
        astore(&A.copyAll[s*32 + b], cpS);
        clr += mnS;
        if (s == 99) astore(&A.clAll[b], clr);
      }
      cov += attn;
      if (tid < 240){
        int seg = tid/80, h4i = tid - seg*80;
        int t0 = seg*86, t1 = (t0+86 < 256) ? t0+86 : 256;
        const float* base = (h4i < 40)
          ? (A.hencB + ((size_t)b*256)*160 + (size_t)h4i*4)
          : (A.hencB + ((size_t)(32+b)*256)*160 + (size_t)(h4i-40)*4);
        float4 accv = {0.f,0.f,0.f,0.f};
        #pragma unroll 4
        for (int t2 = t0; t2 < t1; ++t2){
          float av = attnL[t2];
          float4 ev = *(const float4*)(base + (size_t)t2*160);
          accv.x += av*ev.x; accv.y += av*ev.y; accv.z += av*ev.z; accv.w += av*ev.w;
        }
        *(float4*)(pctx + (seg*80+h4i)*4) = accv;
      }
      __syncthreads();
      if (tid < 80){
        float4 p0 = *(float4*)(pctx + tid*4);
        float4 p1 = *(float4*)(pctx + (80+tid)*4);
        float4 p2v = *(float4*)(pctx + (160+tid)*4);
        float4 cvv;
        cvv.x = p0.x+p1.x+p2v.x; cvv.y = p0.y+p1.y+p2v.y;
        cvv.z = p0.z+p1.z+p2v.z; cvv.w = p0.w+p1.w+p2v.w;
        *(float4*)(ctxL + tid*4) = cvv;
      }
      __syncthreads();
      if (tid < 224){
        int g = tid % 56, seg = tid / 56;
        float acc = 0.f;
        const float* wp = A.W1cT + (size_t)seg*80*56 + g;
        #pragma unroll 4
        for (int q = 0; q < 80; ++q) acc += ctxL[seg*80 + q] * wp[q*56];
        pu[seg*56 + g] = acc;
      } else {
        int l = tid - 224; float acc = 0.f;
        for (int q = l; q < 320; q += 32) acc += ctxL[q]*WcsL[q];
        #pragma unroll
        for (int o=16;o;o>>=1) acc += __shfl_down(acc,o,32);
        if (l==0) astore(&A.ctxWAll[s*32 + b], acc);
      }
      __syncthreads();
      if (tid < 56){
        float upre = aload(&A.uPreAll[(size_t)s*1792 + b*56 + tid]);
        float uu = fast_tanh(upre + pu[tid] + pu[56+tid] + pu[112+tid] + pu[168+tid]);
        astore(&A.uAll[(size_t)s*1792 + b*56 + tid], uu);
      }
      __syncthreads();               // drain: u/scalars at LLC
      if (tid == 0){
        or_bit(flg + FP2W(s,0), 1u << b);
        or_bit(flg + FP2W(s,1), 1u << b);
        or_bit(flg + FP2W(s,2), 1u << b);
        or_bit(flg + FP2W(s,3), 1u << b);
      }
    }
    return;
  }

  // ======== P3: vocab sum-exp, W2 rows pinned in registers (224 WGs) ========
  {
    const int wgv = wg - 65;
    const int vs = (wgv*49998)/224, ve = ((wgv+1)*49998)/224;
    const int v = vs + tid;
    const bool valid = v < ve;
    const int vc = valid ? v : 0;
    float4 w2r[14];
    {
      const float4* wr = (const float4*)(A.W2 + (size_t)vc*56);
      #pragma unroll
      for (int q=0;q<14;++q) w2r[q] = wr[q];
    }
    const float b2v = A.b2[vc];
    float* ulL  = sm;                  // 1792
    float* redW = sm + 1792;           // 128
    int*   idxL = (int*)(sm + 1920);   // 32
    float* red  = sm + 1952;           // 4
    const int lane = tid & 63, wv2 = tid >> 6;
    for (int s = 0; s < 100; ++s){
      int nt3 = (tid < 32) ? A.tgt[tid*100 + s] : 0;
      wait_mask<8>(flg + FP2W(s, wgv & 3), P2_FULL, tid);
      for (int i2 = tid; i2 < 896; i2 += 256){
        float2 u2 = aload2(&A.uAll[(size_t)s*1792 + i2*2]);
        *(float2*)(ulL + i2*2) = u2;
      }
      if (tid < 32){
        int ix = nt3 - 2; ix = ix<0?0:(ix>49997?49997:ix);
        idxL[tid] = ix;
      }
      __syncthreads();
      #pragma unroll 4
      for (int bb=0; bb<32; ++bb){
        const float4* uv = (const float4*)(ulL + bb*56);
        float z = b2v;
        #pragma unroll
        for (int q=0;q<14;++q){
          float4 u4 = uv[q];
          z += w2r[q].x*u4.x + w2r[q].y*u4.y + w2r[q].z*u4.z + w2r[q].w*u4.w;
        }
        if (valid && v == idxL[bb]) astore(&A.zidxAll[s*32+bb], z);
        float sv2 = valid ? __expf(z) : 0.f;
        #pragma unroll
        for (int o=32;o;o>>=1) sv2 += __shfl_down(sv2,o);
        if (lane == 0) redW[wv2*32+bb] = sv2;
      }
      __syncthreads();
      if (tid < 32){
        float tot = redW[tid]+redW[32+tid]+redW[64+tid]+redW[96+tid];
        astore(&A.partAll[(size_t)(s*32+tid)*224 + wgv], tot);
      }
      __syncthreads();
    }
    __syncthreads();
    if (tid == 0) add1(flg + CP3);
    // ---- finalize stage 1 ----
    if (tid == 0){
      while (__hip_atomic_load(flg + CP3, __ATOMIC_RELAXED, MSCOPE) != 224u)
        __builtin_amdgcn_s_sleep(32);
    }
    __syncthreads();
    float nll1 = 0.f;
    for (int p = wgv; p < 3200; p += 224){
      float pv = (tid < 224) ? aload(&A.partAll[(size_t)p*224 + tid]) : 0.f;
      float se = block_sum(pv, red);
      if (tid == 0){
        int s = p >> 5, b = p & 31;
        int nt2 = A.tgt[b*100 + s];
        float xg = aload(&A.ctxWAll[p]) + A.bcs[0] + aload(&A.hWdsAll[p]) + A.es[p];
        float pg = 1.f/(1.f + __expf(-xg));
        float genp = (nt2 >= 2 && nt2 < 50000) ? (__expf(aload(&A.zidxAll[p])) / se) : 0.f;
        float pr = pg*genp + (1.f-pg)*aload(&A.copyAll[p]);
        nll1 += -logf(pr + 1e-9f);
      }
    }
    if (tid == 0) astore(&A.nllWg[wgv], nll1);
    __syncthreads();
    if (tid == 0) add1(flg + CFIN);
    // ---- finalize stage 2 (one WG) ----
    if (wg == 65){
      if (tid == 0){
        while (__hip_atomic_load(flg + CFIN, __ATOMIC_RELAXED, MSCOPE) != 224u)
          __builtin_amdgcn_s_sleep(32);
      }
      __syncthreads();
      float nv = (tid < 224) ? aload(&A.nllWg[tid]) : 0.f;
      float nll = block_sum(nv, red);
      float cv = (tid < 32) ? aload(&A.clAll[tid]) : 0.f;
      float cl = block_sum(cv, red);
      if (tid == 0){ A.out[0]=nll; A.out[1]=cl; A.out[2]=nll + 0.75f*cl; }
    }
  }
}

// ---------------- host launch ----------------
extern "C" void kernel_launch(void* const* d_in, const int* in_sizes, int n_in,
                              void* d_out, int out_size, void* d_ws, size_t ws_size,
                              hipStream_t stream){
  const int*   in_ids = (const int*)  d_in[0];
  const int*   tgt    = (const int*)  d_in[1];
  const float* emb    = (const float*)d_in[3];
  const float* Wi_f   = (const float*)d_in[4];
  const float* Wh_f   = (const float*)d_in[5];
  const float* bi_f   = (const float*)d_in[6];
  const float* bh_f   = (const float*)d_in[7];
  const float* Wi_b   = (const float*)d_in[8];
  const float* Wh_b   = (const float*)d_in[9];
  const float* bi_b   = (const float*)d_in[10];
  const float* bh_b   = (const float*)d_in[11];
  const float* Weh    = (const float*)d_in[12];
  const float* beh    = (const float*)d_in[13];
  const float* Wec    = (const float*)d_in[14];
  const float* bec    = (const float*)d_in[15];
  const float* Wi_d   = (const float*)d_in[16];
  const float* Wh_d   = (const float*)d_in[17];
  const float* bi_d   = (const float*)d_in[18];
  const float* bh_d   = (const float*)d_in[19];
  const float* Wea    = (const float*)d_in[20];
  const float* bea    = (const float*)d_in[21];
  const float* Wda    = (const float*)d_in[22];
  const float* Wca    = (const float*)d_in[23];
  const float* vat    = (const float*)d_in[24];
  const float* W1     = (const float*)d_in[25];
  const float* b1     = (const float*)d_in[26];
  const float* W2     = (const float*)d_in[27];
  const float* b2     = (const float*)d_in[28];
  const float* Wcs    = (const float*)d_in[29];
  const float* bcs    = (const float*)d_in[30];
  const float* Wds    = (const float*)d_in[31];
  const float* Wes    = (const float*)d_in[32];

  float* ws = (float*)d_ws;
  int* iBase = (int*)(ws + oFEnd);
  int* in_mapped = iBase;
  int* cur_ids   = iBase + 8192;
  unsigned* flags = (unsigned*)(iBase + 11392);

  prep_kernel<<<128, 256, 0, stream>>>(in_ids, tgt, in_mapped, cur_ids, flags);
  w1c_transpose<<<70, 256, 0, stream>>>(W1, ws + oW1cT);

  { RGArgs a{in_mapped, emb, Wi_f, bi_f, bh_f, ws + oXf, 640};
    rowgemm<<<1024, 256, 0, stream>>>(a); }
  { RGArgs a{in_mapped, emb, Wi_b, bi_b, bh_b, ws + oXb, 640};
    rowgemm<<<1024, 256, 0, stream>>>(a); }
  { RGArgs a{cur_ids, emb, Wi_d, bi_d, bh_d, ws + oXd, 784};
    rowgemm<<<400, 256, 0, stream>>>(a); }

  es_kernel<<<3200, 64, 0, stream>>>(cur_ids, emb, Wes, ws + oEs);

  { EncArgs ea{ws + oXf, ws + oXb, Wh_f, Wh_b, ws + oHencB, ws + oCT, flags};
    void* ka[] = {&ea};
    hipLaunchCooperativeKernel((void*)enc_scan, dim3(40), dim3(256), ka,
                               (unsigned)((5120 + 32*164)*4), stream); }

  mid_kernel<<<32, 256, 0, stream>>>(ws + oHencB, ws + oCT, Weh, beh, Wec, bec,
                                     ws + oH0, ws + oC0);

  encA_gemm<<<1024, 256, 0, stream>>>(ws + oHencB, Wea, bea, ws + oEncA);

  { DecArgs da{ws + oXd, ws + oHencB, ws + oEncA,
               ws + oH0, ws + oC0,
               Wh_d, Wda, Wca, vat,
               W1, b1, ws + oW1cT, W2, b2, Wcs, bcs, Wds, ws + oEs,
               in_ids, tgt,
               ws + oHdAll, ws + oUAll, ws + oUPreAll, ws + oHwdaAll,
               ws + oHWdsAll, ws + oCtxWAll, ws + oCopyAll,
               ws + oZidxAll, ws + oPartAll, ws + oClAll, ws + oNllWg, (float*)d_out,
               flags};
    void* ka[] = {&da};
    hipLaunchCooperativeKernel((void*)dec_scan, dim3(289), dim3(256), ka,
                               (unsigned)(13584*4), stream); }
}